// Round 6
// baseline (1065.648 us; speedup 1.0000x reference)
//
#include <hip/hip_runtime.h>
#include <cstdint>
#include <cstddef>

// ---------------------------------------------------------------------------
// TransformerMultiViewFusion (MI355X / gfx950), round 6.
//
//  R6 change: ffn_fused_k v2. R5 was barrier-bound (~80 syncthreads/block,
//  14 MFMA/barrier, MfmaUtil 21%). v2 loads W1/W2 MFMA B-fragments DIRECTLY
//  global->VGPR (row-major weights give contiguous 16B/lane; L2-resident;
//  compiler pipelines with vmcnt — no barrier can block it). LDS now just
//  Xs(32K)+Ts(16K)=48KB -> 3 blocks/CU; 17 barriers/block (Ts transpose
//  round-trip only), 64 MFMA/barrier.
//
//  Workspace:
//    X   @ 0          73728*256 bf16   (37,748,736)
//    QKV @ 37748736   73728*768 bf16   (113,246,208)
//    SA  @ 150994944  73728*256 bf16   (37,748,736)
//    Xf  @ 188743680  73728*64  bf16   (9,437,184)
//    WpB @ 198180864  256*64    bf16
//    Wb  @ 226492416  1572864   bf16   (3,145,728)
// ---------------------------------------------------------------------------

typedef __bf16 bf16;
typedef __bf16 bf16x8 __attribute__((ext_vector_type(8)));
typedef float  f32x4  __attribute__((ext_vector_type(4)));

__device__ __forceinline__ void async_copy16(const void* g, void* l)
{
    __builtin_amdgcn_global_load_lds(
        (__attribute__((address_space(1))) void*)g,
        (__attribute__((address_space(3))) void*)l,
        16, 0, 0);
}

// --------------------------------------------------------------------------
// all 5 weight packs in one launch. 1589248 = 6208*256 exactly.
// --------------------------------------------------------------------------
__global__ void pack_all_k(const float* __restrict__ s0, const float* __restrict__ s1,
                           const float* __restrict__ s2, const float* __restrict__ s3,
                           const float* __restrict__ s4,
                           bf16* __restrict__ d0, bf16* __restrict__ d1,
                           bf16* __restrict__ d2, bf16* __restrict__ d3,
                           bf16* __restrict__ d4)
{
    const int i = blockIdx.x * 256 + threadIdx.x;
    if (i < 393216)       d0[i] = (bf16)s0[i];
    else if (i < 524288)  d1[i - 393216] = (bf16)s1[i - 393216];
    else if (i < 1048576) d2[i - 524288] = (bf16)s2[i - 524288];
    else if (i < 1572864) d3[i - 1048576] = (bf16)s3[i - 1048576];
    else                  d4[i - 1572864] = (bf16)s4[i - 1572864];
}

// --------------------------------------------------------------------------
// feat transpose-pack: Xf[t][c] = (bf16)feat[cam][b][c][hw]
// --------------------------------------------------------------------------
__global__ __launch_bounds__(256) void feat_pack_k(const float* __restrict__ feat,
                                                   bf16* __restrict__ Xf)
{
    __shared__ float ft[64][68];

    const int tid  = threadIdx.x;
    const int camb = blockIdx.y;
    const int cam  = camb >> 1;
    const int b    = camb & 1;
    const int hw0  = blockIdx.x * 64;

    const float* fb = feat + (size_t)camb * 64 * 9216 + hw0;
#pragma unroll
    for (int rep = 0; rep < 16; ++rep) {
        const int idx = rep * 256 + tid;
        const int c = idx >> 6, p = idx & 63;
        ft[p][c] = fb[(size_t)c * 9216 + p];
    }
    __syncthreads();

    const int pbase = b * 9216 + hw0;
#pragma unroll
    for (int rep = 0; rep < 2; ++rep) {
        const int idx = rep * 256 + tid;
        const int p = idx >> 3, cc = idx & 7;
        const f32x4 a = *(const f32x4*)(&ft[p][cc * 8]);
        const f32x4 c4 = *(const f32x4*)(&ft[p][cc * 8 + 4]);
        bf16x8 v;
#pragma unroll
        for (int i = 0; i < 4; ++i) { v[i] = (bf16)a[i]; v[4 + i] = (bf16)c4[i]; }
        const size_t t = (size_t)(pbase + p) * 4 + cam;
        *(bf16x8*)(Xf + t * 64 + cc * 8) = v;
    }
}

// --------------------------------------------------------------------------
// GEMM-BT: C[M,N] = A[M,K] @ B[N,K]^T + bias[N], bf16 in/out. 128x128 tile.
// --------------------------------------------------------------------------
template <bool RELU>
__global__ __launch_bounds__(256, 2) void gemm_bt(
    const bf16* __restrict__ A, const bf16* __restrict__ B,
    const float* __restrict__ bias, bf16* __restrict__ C,
    int N, int K)
{
    __shared__ __align__(16) bf16 As[128 * 64];
    __shared__ __align__(16) bf16 Bs[128 * 64];

    const int tid  = threadIdx.x;
    const int lane = tid & 63;
    const int wv   = tid >> 6;
    const int wm   = wv >> 1;
    const int wn   = wv & 1;
    const int bm   = blockIdx.y * 128;
    const int bn   = blockIdx.x * 128;

    const int r8  = lane >> 3;
    const int p8  = lane & 7;
    const int gch = p8 ^ r8;

    const int quad = lane >> 4;
    const int l16  = lane & 15;

    f32x4 acc[4][4] = {};

    for (int k0 = 0; k0 < K; k0 += 64) {
#pragma unroll
        for (int inst = 0; inst < 4; ++inst) {
            const int row = wv * 32 + inst * 8 + r8;
            const bf16* ga = A + (size_t)(bm + row) * K + (k0 + gch * 8);
            const bf16* gb = B + (size_t)(bn + row) * K + (k0 + gch * 8);
            async_copy16(ga, (char*)As + (wv * 4 + inst) * 1024);
            async_copy16(gb, (char*)Bs + (wv * 4 + inst) * 1024);
        }
        __syncthreads();

#pragma unroll
        for (int kk = 0; kk < 2; ++kk) {
            bf16x8 af[4], bfr[4];
            const int lch = kk * 4 + quad;
#pragma unroll
            for (int i = 0; i < 4; ++i) {
                const int m = wm * 64 + i * 16 + l16;
                af[i] = *(const bf16x8*)((const char*)As + (m * 8 + (lch ^ (m & 7))) * 16);
                const int n = wn * 64 + i * 16 + l16;
                bfr[i] = *(const bf16x8*)((const char*)Bs + (n * 8 + (lch ^ (n & 7))) * 16);
            }
#pragma unroll
            for (int i = 0; i < 4; ++i)
#pragma unroll
                for (int j = 0; j < 4; ++j)
                    acc[i][j] = __builtin_amdgcn_mfma_f32_16x16x32_bf16(
                        af[i], bfr[j], acc[i][j], 0, 0, 0);
        }
        __syncthreads();
    }

#pragma unroll
    for (int j = 0; j < 4; ++j) {
        const int n = bn + wn * 64 + j * 16 + l16;
        const float bv = bias[n];
#pragma unroll
        for (int i = 0; i < 4; ++i) {
            const int mb = bm + wm * 64 + i * 16 + quad * 4;
#pragma unroll
            for (int r = 0; r < 4; ++r) {
                float v = acc[i][j][r] + bv;
                if (RELU) v = fmaxf(v, 0.f);
                C[(size_t)(mb + r) * N + n] = (bf16)v;
            }
        }
    }
}

// --------------------------------------------------------------------------
// GEMM-BT + bias + residual + LayerNorm (Wo path, K=256). 128x256 tile.
// --------------------------------------------------------------------------
__global__ __launch_bounds__(256, 2) void gemm_ln_k(
    const bf16* __restrict__ A, const bf16* __restrict__ B,
    const float* __restrict__ bias, const bf16* __restrict__ Xres,
    const float* __restrict__ gam, const float* __restrict__ bet,
    bf16* __restrict__ Xout, int K)
{
    __shared__ __align__(16) bf16 S[24576];
    __shared__ float2 red[128][2];

    const int tid  = threadIdx.x;
    const int lane = tid & 63;
    const int wv   = tid >> 6;
    const int wm   = wv >> 1;
    const int wn   = wv & 1;
    const int bm   = blockIdx.x * 128;
    const int quad = lane >> 4;
    const int l16  = lane & 15;

    f32x4 acc[4][8] = {};

    for (int k0 = 0; k0 < K; k0 += 64) {
#pragma unroll
        for (int s = 0; s < 12; ++s) {
            const int L   = s * 256 + tid;
            const int row = L >> 3;
            const int gch = (L & 7) ^ (row & 7);
            const bf16* g = (row < 128)
                ? A + (size_t)(bm + row) * K + (k0 + gch * 8)
                : B + (size_t)(row - 128) * K + (k0 + gch * 8);
            async_copy16(g, (char*)S + (size_t)L * 16);
        }
        __syncthreads();

#pragma unroll
        for (int kk = 0; kk < 2; ++kk) {
            const int lch = kk * 4 + quad;
            bf16x8 af[4], bfr[8];
#pragma unroll
            for (int i = 0; i < 4; ++i) {
                const int m = wm * 64 + i * 16 + l16;
                af[i] = *(const bf16x8*)((const char*)S + (m * 8 + (lch ^ (m & 7))) * 16);
            }
#pragma unroll
            for (int j = 0; j < 8; ++j) {
                const int n = wn * 128 + j * 16 + l16;
                bfr[j] = *(const bf16x8*)((const char*)S + ((128 + n) * 8 + (lch ^ (n & 7))) * 16);
            }
#pragma unroll
            for (int i = 0; i < 4; ++i)
#pragma unroll
                for (int j = 0; j < 8; ++j)
                    acc[i][j] = __builtin_amdgcn_mfma_f32_16x16x32_bf16(
                        af[i], bfr[j], acc[i][j], 0, 0, 0);
        }
        __syncthreads();
    }

    float bv[8], gv[8], bev[8];
#pragma unroll
    for (int j = 0; j < 8; ++j) {
        const int n = wn * 128 + j * 16 + l16;
        bv[j] = bias[n]; gv[j] = gam[n]; bev[j] = bet[n];
    }

#pragma unroll
    for (int i = 0; i < 4; ++i) {
#pragma unroll
        for (int r = 0; r < 4; ++r) {
            const int rl  = wm * 64 + i * 16 + quad * 4 + r;
            const size_t row = (size_t)(bm + rl);
            float s1 = 0.f, s2 = 0.f;
#pragma unroll
            for (int j = 0; j < 8; ++j) {
                const int n = wn * 128 + j * 16 + l16;
                const float v = acc[i][j][r] + bv[j] + (float)Xres[row * 256 + n];
                acc[i][j][r] = v;
                s1 += v; s2 += v * v;
            }
#pragma unroll
            for (int off = 1; off < 16; off <<= 1) {
                s1 += __shfl_xor(s1, off, 64);
                s2 += __shfl_xor(s2, off, 64);
            }
            if (l16 == 0) red[rl][wn] = make_float2(s1, s2);
        }
    }
    __syncthreads();

#pragma unroll
    for (int i = 0; i < 4; ++i) {
#pragma unroll
        for (int r = 0; r < 4; ++r) {
            const int rl = wm * 64 + i * 16 + quad * 4 + r;
            const float2 p0 = red[rl][0], p1 = red[rl][1];
            const float mu  = (p0.x + p1.x) * (1.f / 256.f);
            const float ex2 = (p0.y + p1.y) * (1.f / 256.f);
            const float rstd = rsqrtf(fmaxf(ex2 - mu * mu, 0.f) + 1e-5f);
            const size_t row = (size_t)(bm + rl);
#pragma unroll
            for (int j = 0; j < 8; ++j) {
                const int n = wn * 128 + j * 16 + l16;
                Xout[row * 256 + n] = (bf16)((acc[i][j][r] - mu) * rstd * gv[j] + bev[j]);
            }
        }
    }
}

// --------------------------------------------------------------------------
// Fused FFN v2: Xout = LN(X + relu(X@W1^T+b1)@W2^T + b2)*gam + bet, in-place.
// 64-row tile, grid 1152, 4 waves 2x2. 8 hidden chunks of 128.
// W1/W2 B-fragments loaded DIRECTLY global->VGPR (no LDS stage, no barrier):
// lane(l16,quad) reads 16B at W[n(l16)][kk*32+quad*8] — 16 rows x 64B/instr.
// LDS: Xs 64x256 (32KB) | Ts 64x128 (16KB, red[] aliases it) = 48KB -> 3/CU.
// Barriers: 1 (Xs) + 2/hc (Ts write/read) + 1 (red alias) = 18.
// --------------------------------------------------------------------------
__global__ __launch_bounds__(256, 3) void ffn_fused_k(
    const bf16* __restrict__ X,
    const bf16* __restrict__ W1, const float* __restrict__ b1,
    const bf16* __restrict__ W2, const float* __restrict__ b2,
    const float* __restrict__ gam, const float* __restrict__ bet,
    bf16* __restrict__ Xout)
{
    __shared__ __align__(16) char smem[49152];
    bf16* Xs = (bf16*)smem;                       // 64 x 256 (32 slots/row)
    bf16* Ts = (bf16*)(smem + 32768);             // 64 x 128 (16 slots/row)
    float2 (*red)[2] = (float2 (*)[2])(void*)(smem + 32768);   // aliases Ts

    const int tid  = threadIdx.x;
    const int lane = tid & 63;
    const int wv   = tid >> 6;
    const int wm   = wv >> 1;
    const int wn   = wv & 1;
    const int quad = lane >> 4;
    const int l16  = lane & 15;
    const int bm   = blockIdx.x * 64;

    // load Xs once: 2048 x 16B
#pragma unroll
    for (int it = 0; it < 8; ++it) {
        const int L = it * 256 + tid;
        const int row = L >> 5, slot = L & 31;
        const int gch = (slot & 24) | ((slot ^ row) & 7);
        async_copy16(X + (size_t)(bm + row) * 256 + gch * 8,
                     (char*)Xs + (size_t)L * 16);
    }
    __syncthreads();

    f32x4 acc2[2][8] = {};

#pragma unroll 1
    for (int hc = 0; hc < 8; ++hc) {
        f32x4 accA[2][4] = {};

        // ---- phase A: accA = Xs @ W1c^T  (weights direct from global/L2)
#pragma unroll
        for (int kk = 0; kk < 8; ++kk) {
            bf16x8 af[2], bfr[4];
            const int gc = kk * 4 + quad;
#pragma unroll
            for (int i = 0; i < 2; ++i) {
                const int m  = wm * 32 + i * 16 + l16;
                const int sl = (gc & 24) | ((gc ^ m) & 7);
                af[i] = *(const bf16x8*)((const char*)Xs + (m * 32 + sl) * 16);
            }
#pragma unroll
            for (int j = 0; j < 4; ++j) {
                const int h = hc * 128 + wn * 64 + j * 16 + l16;
                bfr[j] = *(const bf16x8*)(W1 + (size_t)h * 256 + kk * 32 + quad * 8);
            }
#pragma unroll
            for (int i = 0; i < 2; ++i)
#pragma unroll
                for (int j = 0; j < 4; ++j)
                    accA[i][j] = __builtin_amdgcn_mfma_f32_16x16x32_bf16(
                        af[i], bfr[j], accA[i][j], 0, 0, 0);
        }

        __syncthreads();   // previous phase-B reads of Ts complete

        // ---- write Ts = relu(accA + b1)
#pragma unroll
        for (int j = 0; j < 4; ++j) {
            const int h  = wn * 64 + j * 16 + l16;
            const float bb = b1[hc * 128 + h];
            const int g  = h >> 3;
#pragma unroll
            for (int i = 0; i < 2; ++i)
#pragma unroll
                for (int r = 0; r < 4; ++r) {
                    const int m  = wm * 32 + i * 16 + quad * 4 + r;
                    const int sl = (g & 8) | ((g ^ m) & 7);
                    const float v = fmaxf(accA[i][j][r] + bb, 0.f);
                    *((bf16*)((char*)Ts + (m * 16 + sl) * 16 + (h & 7) * 2)) = (bf16)v;
                }
        }
        __syncthreads();

        // ---- phase B: acc2 += Ts @ W2c^T (W2 direct from global/L2)
#pragma unroll
        for (int kk = 0; kk < 4; ++kk) {
            const int tc = kk * 4 + quad;
            bf16x8 af[2], bfr[8];
#pragma unroll
            for (int i = 0; i < 2; ++i) {
                const int m  = wm * 32 + i * 16 + l16;
                const int sl = (tc & 8) | ((tc ^ m) & 7);
                af[i] = *(const bf16x8*)((const char*)Ts + (m * 16 + sl) * 16);
            }
#pragma unroll
            for (int j = 0; j < 8; ++j) {
                const int n = wn * 128 + j * 16 + l16;
                bfr[j] = *(const bf16x8*)(W2 + (size_t)n * 1024 + hc * 128 + kk * 32 + quad * 8);
            }
#pragma unroll
            for (int i = 0; i < 2; ++i)
#pragma unroll
                for (int j = 0; j < 8; ++j)
                    acc2[i][j] = __builtin_amdgcn_mfma_f32_16x16x32_bf16(
                        af[i], bfr[j], acc2[i][j], 0, 0, 0);
        }
    }

    __syncthreads();   // last Ts reads done before red[] aliases it

    // ---- epilogue: bias + residual + LayerNorm
    float bv[8], gv[8], bev[8];
#pragma unroll
    for (int j = 0; j < 8; ++j) {
        const int n = wn * 128 + j * 16 + l16;
        bv[j] = b2[n]; gv[j] = gam[n]; bev[j] = bet[n];
    }

#pragma unroll
    for (int i = 0; i < 2; ++i) {
#pragma unroll
        for (int r = 0; r < 4; ++r) {
            const int rl = wm * 32 + i * 16 + quad * 4 + r;
            const size_t row = (size_t)(bm + rl);
            float s1 = 0.f, s2 = 0.f;
#pragma unroll
            for (int j = 0; j < 8; ++j) {
                const int n = wn * 128 + j * 16 + l16;
                const float v = acc2[i][j][r] + bv[j] + (float)X[row * 256 + n];
                acc2[i][j][r] = v;
                s1 += v; s2 += v * v;
            }
#pragma unroll
            for (int off = 1; off < 16; off <<= 1) {
                s1 += __shfl_xor(s1, off, 64);
                s2 += __shfl_xor(s2, off, 64);
            }
            if (l16 == 0) red[rl][wn] = make_float2(s1, s2);
        }
    }
    __syncthreads();

#pragma unroll
    for (int i = 0; i < 2; ++i) {
#pragma unroll
        for (int r = 0; r < 4; ++r) {
            const int rl = wm * 32 + i * 16 + quad * 4 + r;
            const float2 p0 = red[rl][0], p1 = red[rl][1];
            const float mu  = (p0.x + p1.x) * (1.f / 256.f);
            const float ex2 = (p0.y + p1.y) * (1.f / 256.f);
            const float rstd = rsqrtf(fmaxf(ex2 - mu * mu, 0.f) + 1e-5f);
            const size_t row = (size_t)(bm + rl);
#pragma unroll
            for (int j = 0; j < 8; ++j) {
                const int n = wn * 128 + j * 16 + l16;
                Xout[row * 256 + n] = (bf16)((acc2[i][j][r] - mu) * rstd * gv[j] + bev[j]);
            }
        }
    }
}

// --------------------------------------------------------------------------
// attention: per sequence (4 tokens), 8 heads x dh=32, softmax over 4 keys.
// --------------------------------------------------------------------------
__global__ __launch_bounds__(256) void attention_k(const bf16* __restrict__ QKV,
                                                   bf16* __restrict__ SA)
{
    __shared__ float qf[4][4][768];
    __shared__ float sc[4][8][4][4];

    const int tid  = threadIdx.x;
    const int wv   = tid >> 6;
    const int lane = tid & 63;
    const int s    = blockIdx.x * 4 + wv;

    const bf16* base = QKV + (size_t)s * 4 * 768;
    for (int idx = lane; idx < 3072; idx += 64)
        qf[wv][idx / 768][idx % 768] = (float)base[idx];
    __syncthreads();

#pragma unroll
    for (int rep = 0; rep < 2; ++rep) {
        const int t = rep * 64 + lane;
        const int h = t >> 4, i = (t >> 2) & 3, j = t & 3;
        const float* q = &qf[wv][i][h * 32];
        const float* k = &qf[wv][j][256 + h * 32];
        float a = 0.f;
#pragma unroll
        for (int dd = 0; dd < 32; ++dd) {
            const int d = (dd + lane) & 31;
            a += q[d] * k[d];
        }
        sc[wv][h][i][j] = a * 0.17677669529663687f;
    }
    __syncthreads();

    if (lane < 32) {
        const int h = lane >> 2, i = lane & 3;
        float s0 = sc[wv][h][i][0], s1 = sc[wv][h][i][1];
        float s2 = sc[wv][h][i][2], s3 = sc[wv][h][i][3];
        float m = fmaxf(fmaxf(s0, s1), fmaxf(s2, s3));
        float e0 = expf(s0 - m), e1 = expf(s1 - m);
        float e2 = expf(s2 - m), e3 = expf(s3 - m);
        float inv = 1.f / (e0 + e1 + e2 + e3);
        sc[wv][h][i][0] = e0 * inv;
        sc[wv][h][i][1] = e1 * inv;
        sc[wv][h][i][2] = e2 * inv;
        sc[wv][h][i][3] = e3 * inv;
    }
    __syncthreads();

#pragma unroll
    for (int rep = 0; rep < 16; ++rep) {
        const int idx = rep * 64 + lane;
        const int i = idx >> 8, col = idx & 255;
        const int h = col >> 5;
        float a = 0.f;
#pragma unroll
        for (int j = 0; j < 4; ++j)
            a += sc[wv][h][i][j] * qf[wv][j][512 + col];
        SA[(size_t)(s * 4 + i) * 256 + col] = (bf16)a;
    }
}

// --------------------------------------------------------------------------
// out[b][c][hw] = sum_e (mean_cam X[p*4+cam][e]) * Wout[c][e] + bout[c]
// --------------------------------------------------------------------------
__global__ __launch_bounds__(256) void out_proj_k(const bf16* __restrict__ X,
                                                  const float* __restrict__ Wout,
                                                  const float* __restrict__ bout,
                                                  float* __restrict__ out)
{
    __shared__ float fused[16][260];
    const int tid = threadIdx.x;
    const int p0  = blockIdx.x * 16;

#pragma unroll
    for (int it = 0; it < 16; ++it) {
        const int idx = it * 256 + tid;
        const int pix = idx >> 8, e = idx & 255;
        const size_t base = (size_t)(p0 + pix) * 1024 + e;
        const float s = (float)X[base] + (float)X[base + 256] +
                        (float)X[base + 512] + (float)X[base + 768];
        fused[pix][e] = s * 0.25f;
    }
    __syncthreads();

    const int pix = tid & 15;
    const int c0  = tid >> 4;
    const int p   = p0 + pix;
    const int b   = p / 9216;
    const int hw  = p % 9216;
#pragma unroll
    for (int it = 0; it < 4; ++it) {
        const int c = it * 16 + c0;
        const float* w = Wout + c * 256;
        float acc = bout[c];
#pragma unroll 8
        for (int e = 0; e < 256; ++e) acc += fused[pix][e] * w[e];
        out[((size_t)b * 64 + c) * 9216 + hw] = acc;
    }
}

// --------------------------------------------------------------------------
extern "C" void kernel_launch(void* const* d_in, const int* in_sizes, int n_in,
                              void* d_out, int out_size, void* d_ws, size_t ws_size,
                              hipStream_t stream)
{
    const float* features = (const float*)d_in[0];
    const float* Wp   = (const float*)d_in[1];
    const float* bp   = (const float*)d_in[2];
    const float* Wqkv = (const float*)d_in[3];
    const float* bqkv = (const float*)d_in[4];
    const float* Wo   = (const float*)d_in[5];
    const float* bo   = (const float*)d_in[6];
    const float* W1   = (const float*)d_in[7];
    const float* b1   = (const float*)d_in[8];
    const float* W2   = (const float*)d_in[9];
    const float* b2   = (const float*)d_in[10];
    const float* g1   = (const float*)d_in[11];
    const float* be1  = (const float*)d_in[12];
    const float* g2   = (const float*)d_in[13];
    const float* be2  = (const float*)d_in[14];
    const float* Wout = (const float*)d_in[15];
    const float* bout = (const float*)d_in[16];
    float* out = (float*)d_out;

    char* ws = (char*)d_ws;
    bf16* X   = (bf16*)(ws);                    // 73728*256
    bf16* QKV = (bf16*)(ws + 37748736ull);      // 73728*768
    bf16* SAb = (bf16*)(ws + 150994944ull);     // 73728*256
    bf16* Xf  = (bf16*)(ws + 188743680ull);     // 73728*64
    bf16* WpB = (bf16*)(ws + 198180864ull);     // 256*64
    bf16* Wb  = (bf16*)(ws + 226492416ull);     // packed bf16 weights

    bf16* WqkvB = Wb;                  // 2 x 768*256
    bf16* WoB   = Wb + 393216;         // 2 x 256*256
    bf16* W1B   = Wb + 524288;         // 2 x 1024*256
    bf16* W2B   = Wb + 1048576;        // 2 x 256*1024

    pack_all_k<<<6208, 256, 0, stream>>>(Wqkv, Wo, W1, W2, Wp,
                                         WqkvB, WoB, W1B, W2B, WpB);

    feat_pack_k<<<dim3(144, 8), 256, 0, stream>>>(features, Xf);
    gemm_bt<false><<<dim3(2, 576), 256, 0, stream>>>(Xf, WpB, bp, X, 256, 64);

    for (int l = 0; l < 2; ++l) {
        gemm_bt<false><<<dim3(6, 576), 256, 0, stream>>>(
            X, WqkvB + l * 196608, bqkv + l * 768, QKV, 768, 256);
        attention_k<<<4608, 256, 0, stream>>>(QKV, SAb);
        gemm_ln_k<<<576, 256, 0, stream>>>(
            SAb, WoB + l * 65536, bo + l * 256, X,
            g1 + l * 256, be1 + l * 256, X, 256);
        ffn_fused_k<<<1152, 256, 0, stream>>>(
            X, W1B + l * 262144, b1 + l * 1024,
            W2B + l * 262144, b2 + l * 256,
            g2 + l * 256, be2 + l * 256, X);
    }

    out_proj_k<<<1152, 256, 0, stream>>>(X, Wout, bout, out);
}

// Round 7
// 648.089 us; speedup vs baseline: 1.6443x; 1.6443x over previous
//
#include <hip/hip_runtime.h>
#include <cstdint>
#include <cstddef>

// ---------------------------------------------------------------------------
// TransformerMultiViewFusion (MI355X / gfx950), round 7.
//
//  R7 changes (R6 direct-VGPR weights REVERTED — it spilled: WRITE_SIZE
//  36.9->71.4MB = scratch traffic, VGPR 84, 341us):
//   * ffn_fused_k v3: R5's LDS-staged weights + ping-pong 16KB stage
//     buffers. Each step prefetches buf[s+1] BEFORE the 16-MFMA consume of
//     buf[s], so the pre-barrier vmcnt drain has ~150cyc of cover (R5 had
//     zero: stage->barrier back-to-back, MfmaUtil 21%).
//     LDS: Xs 32K | Ts 16K (red aliases) | 2x16K stage = 80KB -> 2 blk/CU.
//     W2 staged in paired-row swizzle: fragment reads 2-way (free).
//     Residual read from Xs (LDS) instead of global.
//   * attention_k v2: staging 48 scalar bf16 loads/thread -> 6x bf16x8;
//     PV loop float4 + 8B stores.
//
//  Workspace: X@0 | QKV@37748736 | SA@150994944 | Xf@188743680 |
//             WpB@198180864 | Wb@226492416
// ---------------------------------------------------------------------------

typedef __bf16 bf16;
typedef __bf16 bf16x8 __attribute__((ext_vector_type(8)));
typedef __bf16 bf16x4 __attribute__((ext_vector_type(4)));
typedef float  f32x4  __attribute__((ext_vector_type(4)));

__device__ __forceinline__ void async_copy16(const void* g, void* l)
{
    __builtin_amdgcn_global_load_lds(
        (__attribute__((address_space(1))) void*)g,
        (__attribute__((address_space(3))) void*)l,
        16, 0, 0);
}

// --------------------------------------------------------------------------
// all 5 weight packs in one launch. 1589248 = 6208*256 exactly.
// --------------------------------------------------------------------------
__global__ void pack_all_k(const float* __restrict__ s0, const float* __restrict__ s1,
                           const float* __restrict__ s2, const float* __restrict__ s3,
                           const float* __restrict__ s4,
                           bf16* __restrict__ d0, bf16* __restrict__ d1,
                           bf16* __restrict__ d2, bf16* __restrict__ d3,
                           bf16* __restrict__ d4)
{
    const int i = blockIdx.x * 256 + threadIdx.x;
    if (i < 393216)       d0[i] = (bf16)s0[i];
    else if (i < 524288)  d1[i - 393216] = (bf16)s1[i - 393216];
    else if (i < 1048576) d2[i - 524288] = (bf16)s2[i - 524288];
    else if (i < 1572864) d3[i - 1048576] = (bf16)s3[i - 1048576];
    else                  d4[i - 1572864] = (bf16)s4[i - 1572864];
}

// --------------------------------------------------------------------------
// feat transpose-pack: Xf[t][c] = (bf16)feat[cam][b][c][hw]
// --------------------------------------------------------------------------
__global__ __launch_bounds__(256) void feat_pack_k(const float* __restrict__ feat,
                                                   bf16* __restrict__ Xf)
{
    __shared__ float ft[64][68];

    const int tid  = threadIdx.x;
    const int camb = blockIdx.y;
    const int cam  = camb >> 1;
    const int b    = camb & 1;
    const int hw0  = blockIdx.x * 64;

    const float* fb = feat + (size_t)camb * 64 * 9216 + hw0;
#pragma unroll
    for (int rep = 0; rep < 16; ++rep) {
        const int idx = rep * 256 + tid;
        const int c = idx >> 6, p = idx & 63;
        ft[p][c] = fb[(size_t)c * 9216 + p];
    }
    __syncthreads();

    const int pbase = b * 9216 + hw0;
#pragma unroll
    for (int rep = 0; rep < 2; ++rep) {
        const int idx = rep * 256 + tid;
        const int p = idx >> 3, cc = idx & 7;
        const f32x4 a = *(const f32x4*)(&ft[p][cc * 8]);
        const f32x4 c4 = *(const f32x4*)(&ft[p][cc * 8 + 4]);
        bf16x8 v;
#pragma unroll
        for (int i = 0; i < 4; ++i) { v[i] = (bf16)a[i]; v[4 + i] = (bf16)c4[i]; }
        const size_t t = (size_t)(pbase + p) * 4 + cam;
        *(bf16x8*)(Xf + t * 64 + cc * 8) = v;
    }
}

// --------------------------------------------------------------------------
// GEMM-BT: C[M,N] = A[M,K] @ B[N,K]^T + bias[N], bf16 in/out. 128x128 tile.
// --------------------------------------------------------------------------
template <bool RELU>
__global__ __launch_bounds__(256, 2) void gemm_bt(
    const bf16* __restrict__ A, const bf16* __restrict__ B,
    const float* __restrict__ bias, bf16* __restrict__ C,
    int N, int K)
{
    __shared__ __align__(16) bf16 As[128 * 64];
    __shared__ __align__(16) bf16 Bs[128 * 64];

    const int tid  = threadIdx.x;
    const int lane = tid & 63;
    const int wv   = tid >> 6;
    const int wm   = wv >> 1;
    const int wn   = wv & 1;
    const int bm   = blockIdx.y * 128;
    const int bn   = blockIdx.x * 128;

    const int r8  = lane >> 3;
    const int p8  = lane & 7;
    const int gch = p8 ^ r8;

    const int quad = lane >> 4;
    const int l16  = lane & 15;

    f32x4 acc[4][4] = {};

    for (int k0 = 0; k0 < K; k0 += 64) {
#pragma unroll
        for (int inst = 0; inst < 4; ++inst) {
            const int row = wv * 32 + inst * 8 + r8;
            const bf16* ga = A + (size_t)(bm + row) * K + (k0 + gch * 8);
            const bf16* gb = B + (size_t)(bn + row) * K + (k0 + gch * 8);
            async_copy16(ga, (char*)As + (wv * 4 + inst) * 1024);
            async_copy16(gb, (char*)Bs + (wv * 4 + inst) * 1024);
        }
        __syncthreads();

#pragma unroll
        for (int kk = 0; kk < 2; ++kk) {
            bf16x8 af[4], bfr[4];
            const int lch = kk * 4 + quad;
#pragma unroll
            for (int i = 0; i < 4; ++i) {
                const int m = wm * 64 + i * 16 + l16;
                af[i] = *(const bf16x8*)((const char*)As + (m * 8 + (lch ^ (m & 7))) * 16);
                const int n = wn * 64 + i * 16 + l16;
                bfr[i] = *(const bf16x8*)((const char*)Bs + (n * 8 + (lch ^ (n & 7))) * 16);
            }
#pragma unroll
            for (int i = 0; i < 4; ++i)
#pragma unroll
                for (int j = 0; j < 4; ++j)
                    acc[i][j] = __builtin_amdgcn_mfma_f32_16x16x32_bf16(
                        af[i], bfr[j], acc[i][j], 0, 0, 0);
        }
        __syncthreads();
    }

#pragma unroll
    for (int j = 0; j < 4; ++j) {
        const int n = bn + wn * 64 + j * 16 + l16;
        const float bv = bias[n];
#pragma unroll
        for (int i = 0; i < 4; ++i) {
            const int mb = bm + wm * 64 + i * 16 + quad * 4;
#pragma unroll
            for (int r = 0; r < 4; ++r) {
                float v = acc[i][j][r] + bv;
                if (RELU) v = fmaxf(v, 0.f);
                C[(size_t)(mb + r) * N + n] = (bf16)v;
            }
        }
    }
}

// --------------------------------------------------------------------------
// GEMM-BT + bias + residual + LayerNorm (Wo path, K=256). 128x256 tile.
// --------------------------------------------------------------------------
__global__ __launch_bounds__(256, 2) void gemm_ln_k(
    const bf16* __restrict__ A, const bf16* __restrict__ B,
    const float* __restrict__ bias, const bf16* __restrict__ Xres,
    const float* __restrict__ gam, const float* __restrict__ bet,
    bf16* __restrict__ Xout, int K)
{
    __shared__ __align__(16) bf16 S[24576];
    __shared__ float2 red[128][2];

    const int tid  = threadIdx.x;
    const int lane = tid & 63;
    const int wv   = tid >> 6;
    const int wm   = wv >> 1;
    const int wn   = wv & 1;
    const int bm   = blockIdx.x * 128;
    const int quad = lane >> 4;
    const int l16  = lane & 15;

    f32x4 acc[4][8] = {};

    for (int k0 = 0; k0 < K; k0 += 64) {
#pragma unroll
        for (int s = 0; s < 12; ++s) {
            const int L   = s * 256 + tid;
            const int row = L >> 3;
            const int gch = (L & 7) ^ (row & 7);
            const bf16* g = (row < 128)
                ? A + (size_t)(bm + row) * K + (k0 + gch * 8)
                : B + (size_t)(row - 128) * K + (k0 + gch * 8);
            async_copy16(g, (char*)S + (size_t)L * 16);
        }
        __syncthreads();

#pragma unroll
        for (int kk = 0; kk < 2; ++kk) {
            const int lch = kk * 4 + quad;
            bf16x8 af[4], bfr[8];
#pragma unroll
            for (int i = 0; i < 4; ++i) {
                const int m = wm * 64 + i * 16 + l16;
                af[i] = *(const bf16x8*)((const char*)S + (m * 8 + (lch ^ (m & 7))) * 16);
            }
#pragma unroll
            for (int j = 0; j < 8; ++j) {
                const int n = wn * 128 + j * 16 + l16;
                bfr[j] = *(const bf16x8*)((const char*)S + ((128 + n) * 8 + (lch ^ (n & 7))) * 16);
            }
#pragma unroll
            for (int i = 0; i < 4; ++i)
#pragma unroll
                for (int j = 0; j < 8; ++j)
                    acc[i][j] = __builtin_amdgcn_mfma_f32_16x16x32_bf16(
                        af[i], bfr[j], acc[i][j], 0, 0, 0);
        }
        __syncthreads();
    }

    float bv[8], gv[8], bev[8];
#pragma unroll
    for (int j = 0; j < 8; ++j) {
        const int n = wn * 128 + j * 16 + l16;
        bv[j] = bias[n]; gv[j] = gam[n]; bev[j] = bet[n];
    }

#pragma unroll
    for (int i = 0; i < 4; ++i) {
#pragma unroll
        for (int r = 0; r < 4; ++r) {
            const int rl  = wm * 64 + i * 16 + quad * 4 + r;
            const size_t row = (size_t)(bm + rl);
            float s1 = 0.f, s2 = 0.f;
#pragma unroll
            for (int j = 0; j < 8; ++j) {
                const int n = wn * 128 + j * 16 + l16;
                const float v = acc[i][j][r] + bv[j] + (float)Xres[row * 256 + n];
                acc[i][j][r] = v;
                s1 += v; s2 += v * v;
            }
#pragma unroll
            for (int off = 1; off < 16; off <<= 1) {
                s1 += __shfl_xor(s1, off, 64);
                s2 += __shfl_xor(s2, off, 64);
            }
            if (l16 == 0) red[rl][wn] = make_float2(s1, s2);
        }
    }
    __syncthreads();

#pragma unroll
    for (int i = 0; i < 4; ++i) {
#pragma unroll
        for (int r = 0; r < 4; ++r) {
            const int rl = wm * 64 + i * 16 + quad * 4 + r;
            const float2 p0 = red[rl][0], p1 = red[rl][1];
            const float mu  = (p0.x + p1.x) * (1.f / 256.f);
            const float ex2 = (p0.y + p1.y) * (1.f / 256.f);
            const float rstd = rsqrtf(fmaxf(ex2 - mu * mu, 0.f) + 1e-5f);
            const size_t row = (size_t)(bm + rl);
#pragma unroll
            for (int j = 0; j < 8; ++j) {
                const int n = wn * 128 + j * 16 + l16;
                Xout[row * 256 + n] = (bf16)((acc[i][j][r] - mu) * rstd * gv[j] + bev[j]);
            }
        }
    }
}

// --------------------------------------------------------------------------
// ffn stage step s (0..63): hc = s>>3; q = s&7.
//  q<4 : W1 quarter  [128 h][64 k]  8 chunks/row, slot = c ^ (row&7)
//  q>=4: W2 quarter  [256 n][32 k]  paired rows: LDS row = n>>1, 8 slots =
//        ((n&1)*4 + c) ^ ((n>>1)&7)  -> fragment reads 2-way (free)
// --------------------------------------------------------------------------
__device__ __forceinline__ void ffn_stage(int s, const bf16* __restrict__ W1,
                                          const bf16* __restrict__ W2,
                                          char* buf, int tid)
{
    const int hc = s >> 3;
    const int q  = s & 7;
    if (q < 4) {
#pragma unroll
        for (int it = 0; it < 4; ++it) {
            const int L = it * 256 + tid;
            const int row = L >> 3, psl = L & 7;
            const int c = psl ^ (row & 7);
            async_copy16(W1 + (size_t)(hc * 128 + row) * 256 + q * 64 + c * 8,
                         buf + (size_t)L * 16);
        }
    } else {
#pragma unroll
        for (int it = 0; it < 4; ++it) {
            const int L = it * 256 + tid;
            const int r128 = L >> 3, psl = L & 7;
            const int g = psl ^ (r128 & 7);
            const int n = r128 * 2 + (g >> 2);
            const int c = g & 3;
            async_copy16(W2 + (size_t)n * 1024 + hc * 128 + (q - 4) * 32 + c * 8,
                         buf + (size_t)L * 16);
        }
    }
}

// --------------------------------------------------------------------------
// Fused FFN v3: Xout = LN(X + relu(X@W1^T+b1)@W2^T + b2)*gam + bet, in-place.
// 64-row tile, grid 1152, 4 waves 2x2. 8 hidden chunks of 128.
// Ping-pong 16KB weight stage: prefetch buf[s+1] before consuming buf[s].
// LDS: Xs 32K | Ts 16K (red aliases) | stage 2x16K = 80KB -> 2 blocks/CU.
// --------------------------------------------------------------------------
__global__ __launch_bounds__(256, 2) void ffn_fused_k(
    const bf16* __restrict__ X,
    const bf16* __restrict__ W1, const float* __restrict__ b1,
    const bf16* __restrict__ W2, const float* __restrict__ b2,
    const float* __restrict__ gam, const float* __restrict__ bet,
    bf16* __restrict__ Xout)
{
    __shared__ __align__(16) char smem[81920];
    bf16* Xs = (bf16*)smem;                       // 64 x 256 (32 slots/row)
    bf16* Ts = (bf16*)(smem + 32768);             // 64 x 128 (16 slots/row)
    float2 (*red)[2] = (float2 (*)[2])(void*)(smem + 32768);   // aliases Ts
    char* stg = smem + 49152;                     // 2 x 16KB

    const int tid  = threadIdx.x;
    const int lane = tid & 63;
    const int wv   = tid >> 6;
    const int wm   = wv >> 1;
    const int wn   = wv & 1;
    const int quad = lane >> 4;
    const int l16  = lane & 15;
    const int bm   = blockIdx.x * 64;

    // prologue: Xs (2048 x 16B) + first weight step
#pragma unroll
    for (int it = 0; it < 8; ++it) {
        const int L = it * 256 + tid;
        const int row = L >> 5, slot = L & 31;
        const int gch = (slot & 24) | ((slot ^ row) & 7);
        async_copy16(X + (size_t)(bm + row) * 256 + gch * 8,
                     (char*)Xs + (size_t)L * 16);
    }
    ffn_stage(0, W1, W2, stg, tid);
    __syncthreads();

    f32x4 acc2[2][8] = {};

#pragma unroll 1
    for (int hc = 0; hc < 8; ++hc) {
        f32x4 accA[2][4] = {};

        // ---- phase A: accA = Xs @ W1c^T, 4 steps of 64k
#pragma unroll
        for (int q = 0; q < 4; ++q) {
            const int s = hc * 8 + q;
            const char* cur = stg + (size_t)(s & 1) * 16384;
            ffn_stage(s + 1, W1, W2, stg + (size_t)((s + 1) & 1) * 16384, tid);
#pragma unroll
            for (int kk = 0; kk < 2; ++kk) {
                const int ch = kk * 4 + quad;          // buffer chunk 0..7
                const int gc = q * 8 + ch;             // Xs chunk 0..31
                bf16x8 af[2], bfr[4];
#pragma unroll
                for (int i = 0; i < 2; ++i) {
                    const int m  = wm * 32 + i * 16 + l16;
                    const int sl = (gc & 24) | ((gc ^ m) & 7);
                    af[i] = *(const bf16x8*)((const char*)Xs + (m * 32 + sl) * 16);
                }
#pragma unroll
                for (int j = 0; j < 4; ++j) {
                    const int n  = wn * 64 + j * 16 + l16;
                    const int sl = ch ^ (n & 7);
                    bfr[j] = *(const bf16x8*)(cur + (n * 8 + sl) * 16);
                }
#pragma unroll
                for (int i = 0; i < 2; ++i)
#pragma unroll
                    for (int j = 0; j < 4; ++j)
                        accA[i][j] = __builtin_amdgcn_mfma_f32_16x16x32_bf16(
                            af[i], bfr[j], accA[i][j], 0, 0, 0);
            }
            __syncthreads();
        }

        // ---- Ts = relu(accA + b1)
#pragma unroll
        for (int j = 0; j < 4; ++j) {
            const int h  = wn * 64 + j * 16 + l16;
            const float bb = b1[hc * 128 + h];
            const int g  = h >> 3;
#pragma unroll
            for (int i = 0; i < 2; ++i)
#pragma unroll
                for (int r = 0; r < 4; ++r) {
                    const int m  = wm * 32 + i * 16 + quad * 4 + r;
                    const int sl = (g & 8) | ((g ^ m) & 7);
                    const float v = fmaxf(accA[i][j][r] + bb, 0.f);
                    *((bf16*)((char*)Ts + (m * 16 + sl) * 16 + (h & 7) * 2)) = (bf16)v;
                }
        }
        __syncthreads();

        // ---- phase B: acc2 += Ts @ W2c^T, 4 steps of 32k
#pragma unroll
        for (int q = 0; q < 4; ++q) {
            const int s = hc * 8 + 4 + q;
            const char* cur = stg + (size_t)(s & 1) * 16384;
            if (s < 63)
                ffn_stage(s + 1, W1, W2, stg + (size_t)((s + 1) & 1) * 16384, tid);
            const int tc = q * 4 + quad;               // Ts chunk 0..15
            bf16x8 af[2], bfr[8];
#pragma unroll
            for (int i = 0; i < 2; ++i) {
                const int m  = wm * 32 + i * 16 + l16;
                const int sl = (tc & 8) | ((tc ^ m) & 7);
                af[i] = *(const bf16x8*)((const char*)Ts + (m * 16 + sl) * 16);
            }
#pragma unroll
            for (int j = 0; j < 8; ++j) {
                const int n  = wn * 128 + j * 16 + l16;
                const int sl = (((n & 1) * 4 + quad) ^ ((n >> 1) & 7)) & 7;
                bfr[j] = *(const bf16x8*)(cur + ((n >> 1) * 8 + sl) * 16);
            }
#pragma unroll
            for (int i = 0; i < 2; ++i)
#pragma unroll
                for (int j = 0; j < 8; ++j)
                    acc2[i][j] = __builtin_amdgcn_mfma_f32_16x16x32_bf16(
                        af[i], bfr[j], acc2[i][j], 0, 0, 0);
            __syncthreads();
        }
    }

    // ---- epilogue: bias + residual (from Xs) + LayerNorm
    float bv[8], gv[8], bev[8];
#pragma unroll
    for (int j = 0; j < 8; ++j) {
        const int n = wn * 128 + j * 16 + l16;
        bv[j] = b2[n]; gv[j] = gam[n]; bev[j] = bet[n];
    }

#pragma unroll
    for (int i = 0; i < 2; ++i) {
#pragma unroll
        for (int r = 0; r < 4; ++r) {
            const int rl = wm * 32 + i * 16 + quad * 4 + r;
            float s1 = 0.f, s2 = 0.f;
#pragma unroll
            for (int j = 0; j < 8; ++j) {
                const int n  = wn * 128 + j * 16 + l16;
                const int gc = n >> 3;
                const int sl = (gc & 24) | ((gc ^ rl) & 7);
                const float xr = (float)*((const bf16*)((const char*)Xs +
                                   (rl * 32 + sl) * 16 + (n & 7) * 2));
                const float v = acc2[i][j][r] + bv[j] + xr;
                acc2[i][j][r] = v;
                s1 += v; s2 += v * v;
            }
#pragma unroll
            for (int off = 1; off < 16; off <<= 1) {
                s1 += __shfl_xor(s1, off, 64);
                s2 += __shfl_xor(s2, off, 64);
            }
            if (l16 == 0) red[rl][wn] = make_float2(s1, s2);
        }
    }
    __syncthreads();

#pragma unroll
    for (int i = 0; i < 2; ++i) {
#pragma unroll
        for (int r = 0; r < 4; ++r) {
            const int rl = wm * 32 + i * 16 + quad * 4 + r;
            const float2 p0 = red[rl][0], p1 = red[rl][1];
            const float mu  = (p0.x + p1.x) * (1.f / 256.f);
            const float ex2 = (p0.y + p1.y) * (1.f / 256.f);
            const float rstd = rsqrtf(fmaxf(ex2 - mu * mu, 0.f) + 1e-5f);
            const size_t row = (size_t)(bm + rl);
#pragma unroll
            for (int j = 0; j < 8; ++j) {
                const int n = wn * 128 + j * 16 + l16;
                Xout[row * 256 + n] = (bf16)((acc2[i][j][r] - mu) * rstd * gv[j] + bev[j]);
            }
        }
    }
}

// --------------------------------------------------------------------------
// attention v2: per sequence (4 tokens), 8 heads x dh=32, softmax over 4.
// Staging vectorized bf16x8; PV float4; 8B stores.
// --------------------------------------------------------------------------
__global__ __launch_bounds__(256) void attention_k(const bf16* __restrict__ QKV,
                                                   bf16* __restrict__ SA)
{
    __shared__ float qf[4][4][768];
    __shared__ float sc[4][8][4][4];

    const int tid  = threadIdx.x;
    const int wv   = tid >> 6;
    const int lane = tid & 63;
    const int s    = blockIdx.x * 4 + wv;

    const bf16* base = QKV + (size_t)s * 4 * 768;
#pragma unroll
    for (int it = 0; it < 6; ++it) {
        const int idx = it * 64 + lane;        // 0..383 groups of 8
        const bf16x8 v = *(const bf16x8*)(base + idx * 8);
        const int tok = idx / 96;
        const int e   = (idx % 96) * 8;
        f32x4 f0, f1;
#pragma unroll
        for (int i = 0; i < 4; ++i) { f0[i] = (float)v[i]; f1[i] = (float)v[4 + i]; }
        *(f32x4*)(&qf[wv][tok][e])     = f0;
        *(f32x4*)(&qf[wv][tok][e + 4]) = f1;
    }
    __syncthreads();

#pragma unroll
    for (int rep = 0; rep < 2; ++rep) {
        const int t = rep * 64 + lane;
        const int h = t >> 4, i = (t >> 2) & 3, j = t & 3;
        const float* q = &qf[wv][i][h * 32];
        const float* k = &qf[wv][j][256 + h * 32];
        float a = 0.f;
#pragma unroll
        for (int dd = 0; dd < 32; ++dd) {
            const int d = (dd + lane) & 31;
            a += q[d] * k[d];
        }
        sc[wv][h][i][j] = a * 0.17677669529663687f;
    }
    __syncthreads();

    if (lane < 32) {
        const int h = lane >> 2, i = lane & 3;
        float s0 = sc[wv][h][i][0], s1 = sc[wv][h][i][1];
        float s2 = sc[wv][h][i][2], s3 = sc[wv][h][i][3];
        float m = fmaxf(fmaxf(s0, s1), fmaxf(s2, s3));
        float e0 = expf(s0 - m), e1 = expf(s1 - m);
        float e2 = expf(s2 - m), e3 = expf(s3 - m);
        float inv = 1.f / (e0 + e1 + e2 + e3);
        sc[wv][h][i][0] = e0 * inv;
        sc[wv][h][i][1] = e1 * inv;
        sc[wv][h][i][2] = e2 * inv;
        sc[wv][h][i][3] = e3 * inv;
    }
    __syncthreads();

    const int h = lane >> 3;                   // col group = lane*4, h = col>>5
#pragma unroll
    for (int i = 0; i < 4; ++i) {
        f32x4 a = {0.f, 0.f, 0.f, 0.f};
#pragma unroll
        for (int j = 0; j < 4; ++j) {
            const float p = sc[wv][h][i][j];
            const f32x4 v = *(const f32x4*)(&qf[wv][j][512 + lane * 4]);
#pragma unroll
            for (int q = 0; q < 4; ++q) a[q] += p * v[q];
        }
        bf16x4 o;
#pragma unroll
        for (int q = 0; q < 4; ++q) o[q] = (bf16)a[q];
        *(bf16x4*)(SA + (size_t)(s * 4 + i) * 256 + lane * 4) = o;
    }
}

// --------------------------------------------------------------------------
// out[b][c][hw] = sum_e (mean_cam X[p*4+cam][e]) * Wout[c][e] + bout[c]
// --------------------------------------------------------------------------
__global__ __launch_bounds__(256) void out_proj_k(const bf16* __restrict__ X,
                                                  const float* __restrict__ Wout,
                                                  const float* __restrict__ bout,
                                                  float* __restrict__ out)
{
    __shared__ float fused[16][260];
    const int tid = threadIdx.x;
    const int p0  = blockIdx.x * 16;

#pragma unroll
    for (int it = 0; it < 16; ++it) {
        const int idx = it * 256 + tid;
        const int pix = idx >> 8, e = idx & 255;
        const size_t base = (size_t)(p0 + pix) * 1024 + e;
        const float s = (float)X[base] + (float)X[base + 256] +
                        (float)X[base + 512] + (float)X[base + 768];
        fused[pix][e] = s * 0.25f;
    }
    __syncthreads();

    const int pix = tid & 15;
    const int c0  = tid >> 4;
    const int p   = p0 + pix;
    const int b   = p / 9216;
    const int hw  = p % 9216;
#pragma unroll
    for (int it = 0; it < 4; ++it) {
        const int c = it * 16 + c0;
        const float* w = Wout + c * 256;
        float acc = bout[c];
#pragma unroll 8
        for (int e = 0; e < 256; ++e) acc += fused[pix][e] * w[e];
        out[((size_t)b * 64 + c) * 9216 + hw] = acc;
    }
}

// --------------------------------------------------------------------------
extern "C" void kernel_launch(void* const* d_in, const int* in_sizes, int n_in,
                              void* d_out, int out_size, void* d_ws, size_t ws_size,
                              hipStream_t stream)
{
    const float* features = (const float*)d_in[0];
    const float* Wp   = (const float*)d_in[1];
    const float* bp   = (const float*)d_in[2];
    const float* Wqkv = (const float*)d_in[3];
    const float* bqkv = (const float*)d_in[4];
    const float* Wo   = (const float*)d_in[5];
    const float* bo   = (const float*)d_in[6];
    const float* W1   = (const float*)d_in[7];
    const float* b1   = (const float*)d_in[8];
    const float* W2   = (const float*)d_in[9];
    const float* b2   = (const float*)d_in[10];
    const float* g1   = (const float*)d_in[11];
    const float* be1  = (const float*)d_in[12];
    const float* g2   = (const float*)d_in[13];
    const float* be2  = (const float*)d_in[14];
    const float* Wout = (const float*)d_in[15];
    const float* bout = (const float*)d_in[16];
    float* out = (float*)d_out;

    char* ws = (char*)d_ws;
    bf16* X   = (bf16*)(ws);                    // 73728*256
    bf16* QKV = (bf16*)(ws + 37748736ull);      // 73728*768
    bf16* SAb = (bf16*)(ws + 150994944ull);     // 73728*256
    bf16* Xf  = (bf16*)(ws + 188743680ull);     // 73728*64
    bf16* WpB = (bf16*)(ws + 198180864ull);     // 256*64
    bf16* Wb  = (bf16*)(ws + 226492416ull);     // packed bf16 weights

    bf16* WqkvB = Wb;                  // 2 x 768*256
    bf16* WoB   = Wb + 393216;         // 2 x 256*256
    bf16* W1B   = Wb + 524288;         // 2 x 1024*256
    bf16* W2B   = Wb + 1048576;        // 2 x 256*1024

    pack_all_k<<<6208, 256, 0, stream>>>(Wqkv, Wo, W1, W2, Wp,
                                         WqkvB, WoB, W1B, W2B, WpB);

    feat_pack_k<<<dim3(144, 8), 256, 0, stream>>>(features, Xf);
    gemm_bt<false><<<dim3(2, 576), 256, 0, stream>>>(Xf, WpB, bp, X, 256, 64);

    for (int l = 0; l < 2; ++l) {
        gemm_bt<false><<<dim3(6, 576), 256, 0, stream>>>(
            X, WqkvB + l * 196608, bqkv + l * 768, QKV, 768, 256);
        attention_k<<<4608, 256, 0, stream>>>(QKV, SAb);
        gemm_ln_k<<<576, 256, 0, stream>>>(
            SAb, WoB + l * 65536, bo + l * 256, X,
            g1 + l * 256, be1 + l * 256, X, 256);
        ffn_fused_k<<<1152, 256, 0, stream>>>(
            X, W1B + l * 262144, b1 + l * 1024,
            W2B + l * 262144, b2 + l * 256,
            g2 + l * 256, be2 + l * 256, X);
    }

    out_proj_k<<<1152, 256, 0, stream>>>(X, Wout, bout, out);
}